// Round 3
// baseline (618.522 us; speedup 1.0000x reference)
//
#include <hip/hip_runtime.h>

#define D_IN 256
#define D_OUT 64
#define BN_EPS 1e-5f

#define KC 32      // K-chunk
#define BM 128     // nodes per block tile
#define XS 132     // Xs row stride (floats), padded: BM + 4
#define WS 68      // Ws row stride (floats), padded: 64 + 4

typedef __attribute__((ext_vector_type(4))) float floatx4;

// ---- degree ----------------------------------------------------------------
__global__ void k_init_deg(int* __restrict__ deg, int n) {
    int i = blockIdx.x * 256 + threadIdx.x;
    if (i < n) deg[i] = 1;  // self-loop
}

__global__ void k_count_deg(const int* __restrict__ col, int* __restrict__ deg, int E) {
    int e = blockIdx.x * 256 + threadIdx.x;
    if (e < E) atomicAdd(&deg[col[e]], 1);
}

__global__ void k_dinv(float* __restrict__ dinv, int n) {
    int i = blockIdx.x * 256 + threadIdx.x;
    if (i < n) {
        int d = ((const int*)dinv)[i];
        dinv[i] = rsqrtf((float)d);
    }
}

// ---- bn params: sc[c] = gamma/sqrt(var+eps); sh[c] = (bias-mean)*sc + beta --
__global__ void k_bnparams(const float* __restrict__ bias,
                           const float* __restrict__ gamma,
                           const float* __restrict__ beta,
                           const float* __restrict__ rmean,
                           const float* __restrict__ rvar,
                           float* __restrict__ bnsc, float* __restrict__ bnsh) {
    int c = threadIdx.x;
    if (c < D_OUT) {
        float sc = rsqrtf(rvar[c] + BN_EPS) * gamma[c];
        bnsc[c] = sc;
        bnsh[c] = (bias[c] - rmean[c]) * sc + beta[c];
    }
}

// ---- y = dinv * (x @ W^T), fp32 VALU, LDS-tiled; agg initialized to y ------
// Block: 256 threads = (tm 0..31) x (tn 0..7). Thread computes 4 nodes x 8 ch.
// LDS tiles stored transposed (k-major) so inner loop is 3x ds_read_b128.
__global__ __launch_bounds__(256) void k_gemm(
        const float* __restrict__ x, const float* __restrict__ W,
        const float* __restrict__ dinv,
        float* __restrict__ y, float* __restrict__ agg, int n) {
    __shared__ float Xs[KC * XS];
    __shared__ float Ws[KC * WS];

    int t = threadIdx.x;
    int tn = t & 7;        // 8 groups of 8 channels
    int tm = t >> 3;       // 32 groups of 4 nodes
    int m0 = blockIdx.x * BM;

    float acc[4][8];
    #pragma unroll
    for (int i = 0; i < 4; ++i)
        #pragma unroll
        for (int j = 0; j < 8; ++j) acc[i][j] = 0.f;

    for (int ks = 0; ks < D_IN; ks += KC) {
        // stage X chunk: 128 rows x 32 k, transposed into Xs[k][row]
        #pragma unroll
        for (int i = 0; i < 4; ++i) {
            int f = t + 256 * i;          // 0..1023 float4s
            int row = f >> 3;             // 0..127
            int seg = f & 7;              // 0..7 -> k offset seg*4
            int gnode = m0 + row;
            if (gnode >= n) gnode = n - 1;   // clamp (results unused)
            floatx4 v = *(const floatx4*)(x + (size_t)gnode * D_IN + ks + seg * 4);
            #pragma unroll
            for (int j = 0; j < 4; ++j)
                Xs[(seg * 4 + j) * XS + row] = v[j];
        }
        // stage W chunk: 64 rows x 32 k, transposed into Ws[k][c]
        #pragma unroll
        for (int i = 0; i < 2; ++i) {
            int f = t + 256 * i;          // 0..511 float4s
            int c = f >> 3;               // 0..63
            int seg = f & 7;
            floatx4 v = *(const floatx4*)(W + (size_t)c * D_IN + ks + seg * 4);
            #pragma unroll
            for (int j = 0; j < 4; ++j)
                Ws[(seg * 4 + j) * WS + c] = v[j];
        }
        __syncthreads();

        #pragma unroll 4
        for (int k = 0; k < KC; ++k) {
            floatx4 xv  = *(const floatx4*)&Xs[k * XS + tm * 4];
            floatx4 wv0 = *(const floatx4*)&Ws[k * WS + tn * 8];
            floatx4 wv1 = *(const floatx4*)&Ws[k * WS + tn * 8 + 4];
            #pragma unroll
            for (int i = 0; i < 4; ++i) {
                #pragma unroll
                for (int j = 0; j < 4; ++j) {
                    acc[i][j]     = fmaf(xv[i], wv0[j], acc[i][j]);
                    acc[i][j + 4] = fmaf(xv[i], wv1[j], acc[i][j + 4]);
                }
            }
        }
        __syncthreads();
    }

    #pragma unroll
    for (int i = 0; i < 4; ++i) {
        int node = m0 + tm * 4 + i;
        if (node >= n) continue;
        float dv = dinv[node];
        floatx4 o0, o1;
        #pragma unroll
        for (int j = 0; j < 4; ++j) {
            o0[j] = dv * acc[i][j];
            o1[j] = dv * acc[i][j + 4];
        }
        size_t base = (size_t)node * D_OUT + tn * 8;
        *(floatx4*)(y + base)       = o0;
        *(floatx4*)(y + base + 4)   = o1;
        *(floatx4*)(agg + base)     = o0;   // self-loop init
        *(floatx4*)(agg + base + 4) = o1;
    }
}

// ---- edge scatter: one wave per edge, lane = output channel ----------------
// agg[col] += y[row]   (all dinv factors handled outside the edge loop)
__global__ __launch_bounds__(256) void k_scatter(
        const int* __restrict__ ei, const float* __restrict__ y,
        float* __restrict__ agg, int E) {
    int e = blockIdx.x * 4 + (threadIdx.x >> 6);
    if (e >= E) return;
    int lane = threadIdx.x & 63;
    int r = ei[e];       // source
    int c = ei[E + e];   // target
    float v = y[(size_t)r * D_OUT + lane];
    unsafeAtomicAdd(&agg[(size_t)c * D_OUT + lane], v);
}

// ---- fused dinv[c]*agg -> bias/BN/ReLU, float4 in/out ----------------------
__global__ void k_epilogue(const float* __restrict__ agg,
                           const float* __restrict__ dinv,
                           const float* __restrict__ bnsc,
                           const float* __restrict__ bnsh,
                           float* __restrict__ out, int total4) {
    int t = blockIdx.x * 256 + threadIdx.x;
    if (t >= total4) return;
    int base = t * 4;
    int node = base >> 6;           // D_OUT = 64
    int ch = base & (D_OUT - 1);
    float dv = dinv[node];
    floatx4 a = *(const floatx4*)(agg + base);
    floatx4 o;
    #pragma unroll
    for (int j = 0; j < 4; ++j) {
        float v = fmaf(dv * a[j], bnsc[ch + j], bnsh[ch + j]);
        o[j] = v > 0.f ? v : 0.f;
    }
    *(floatx4*)(out + base) = o;
}

extern "C" void kernel_launch(void* const* d_in, const int* in_sizes, int n_in,
                              void* d_out, int out_size, void* d_ws, size_t ws_size,
                              hipStream_t stream) {
    const float* x     = (const float*)d_in[0];
    const int*   ei    = (const int*)d_in[1];
    const float* W     = (const float*)d_in[2];
    const float* bias  = (const float*)d_in[3];
    const float* gamma = (const float*)d_in[4];
    const float* beta  = (const float*)d_in[5];
    const float* rmean = (const float*)d_in[6];
    const float* rvar  = (const float*)d_in[7];
    float* out = (float*)d_out;

    int N = in_sizes[0] / D_IN;
    int E = in_sizes[1] / 2;

    float* dinv = (float*)d_ws;                       // N floats (int during count)
    float* bnsc = dinv + N;                           // 64
    float* bnsh = bnsc + D_OUT;                       // 64
    float* y    = bnsh + D_OUT;                       // N*64 f32
    float* agg  = y + (size_t)N * D_OUT;              // N*64 f32

    k_init_deg<<<(N + 255) / 256, 256, 0, stream>>>((int*)dinv, N);
    k_count_deg<<<(E + 255) / 256, 256, 0, stream>>>(ei + E, (int*)dinv, E);
    k_dinv<<<(N + 255) / 256, 256, 0, stream>>>(dinv, N);
    k_bnparams<<<1, 64, 0, stream>>>(bias, gamma, beta, rmean, rvar, bnsc, bnsh);
    k_gemm<<<(N + BM - 1) / BM, 256, 0, stream>>>(x, W, dinv, y, agg, N);
    k_scatter<<<(E + 3) / 4, 256, 0, stream>>>(ei, y, agg, E);
    k_epilogue<<<(N * D_OUT / 4 + 255) / 256, 256, 0, stream>>>(
        agg, dinv, bnsc, bnsh, out, N * D_OUT / 4);
}

// Round 4
// 491.477 us; speedup vs baseline: 1.2585x; 1.2585x over previous
//
#include <hip/hip_runtime.h>

#define D_IN 256
#define D_OUT 64
#define BN_EPS 1e-5f

#define KC 32      // GEMM K-chunk
#define BM 128     // GEMM nodes per block tile
#define XS 132     // Xs row stride (floats), padded
#define WS 68      // Ws row stride (floats), padded

typedef __attribute__((ext_vector_type(4))) float floatx4;

// ---- zero in-degree counters (ws is poisoned 0xAA before every launch) -----
__global__ void k_zero(int* __restrict__ p, int n) {
    int i = blockIdx.x * 256 + threadIdx.x;
    if (i < n) p[i] = 0;
}

__global__ void k_count(const int* __restrict__ col, int* __restrict__ cnt, int E) {
    int e = blockIdx.x * 256 + threadIdx.x;
    if (e < E) atomicAdd(&cnt[col[e]], 1);
}

// ---- hierarchical exclusive scan of cnt[N] -> off[N+1]; also cursor, dinv --
// s1: per-block (1024 elems) totals
__global__ __launch_bounds__(256) void k_scan1(const int* __restrict__ cnt,
                                               int* __restrict__ blksum, int n) {
    __shared__ int ts[256];
    int b = blockIdx.x, t = threadIdx.x;
    int i0 = b * 1024 + t * 4;
    int s = 0;
    #pragma unroll
    for (int j = 0; j < 4; ++j) { int i = i0 + j; if (i < n) s += cnt[i]; }
    ts[t] = s; __syncthreads();
    for (int o = 128; o > 0; o >>= 1) {
        if (t < o) ts[t] += ts[t + o];
        __syncthreads();
    }
    if (t == 0) blksum[b] = ts[0];
}

// s2: exclusive scan of block sums (<=256 blocks -> N <= 262144)
__global__ __launch_bounds__(256) void k_scan2(const int* __restrict__ blksum,
                                               int* __restrict__ blkoff, int nb) {
    __shared__ int ts[256];
    int t = threadIdx.x;
    int own = (t < nb) ? blksum[t] : 0;
    ts[t] = own; __syncthreads();
    for (int o = 1; o < 256; o <<= 1) {
        int v = (t >= o) ? ts[t - o] : 0;
        __syncthreads();
        ts[t] += v;
        __syncthreads();
    }
    if (t < nb) blkoff[t] = ts[t] - own;
}

// s3: per-block exclusive scan + base; writes off, cursor, off[N], and dinv
__global__ __launch_bounds__(256) void k_scan3(const int* __restrict__ cnt,
                                               const int* __restrict__ blkoff,
                                               int* __restrict__ off,
                                               int* __restrict__ cur,
                                               float* __restrict__ dinv, int n) {
    __shared__ int ts[256];
    int b = blockIdx.x, t = threadIdx.x;
    int i0 = b * 1024 + t * 4;
    int c[4];
    #pragma unroll
    for (int j = 0; j < 4; ++j) { int i = i0 + j; c[j] = (i < n) ? cnt[i] : 0; }
    int tot = c[0] + c[1] + c[2] + c[3];
    ts[t] = tot; __syncthreads();
    for (int o = 1; o < 256; o <<= 1) {
        int v = (t >= o) ? ts[t - o] : 0;
        __syncthreads();
        ts[t] += v;
        __syncthreads();
    }
    int run = blkoff[b] + ts[t] - tot;
    #pragma unroll
    for (int j = 0; j < 4; ++j) {
        int i = i0 + j;
        if (i < n) {
            off[i] = run;
            cur[i] = run;
            dinv[i] = rsqrtf((float)(c[j] + 1));   // +1 self-loop
            run += c[j];
            if (i == n - 1) off[n] = run;
        }
    }
}

// ---- bucket source indices by target node (CSR fill) -----------------------
__global__ void k_fill(const int* __restrict__ ei, int* __restrict__ cur,
                       int* __restrict__ srcs, int E) {
    int e = blockIdx.x * 256 + threadIdx.x;
    if (e < E) {
        int c = ei[E + e];
        int p = atomicAdd(&cur[c], 1);
        srcs[p] = ei[e];
    }
}

// ---- bn params: sc[c] = gamma/sqrt(var+eps); sh[c] = (bias-mean)*sc + beta --
__global__ void k_bnparams(const float* __restrict__ bias,
                           const float* __restrict__ gamma,
                           const float* __restrict__ beta,
                           const float* __restrict__ rmean,
                           const float* __restrict__ rvar,
                           float* __restrict__ bnsc, float* __restrict__ bnsh) {
    int c = threadIdx.x;
    if (c < D_OUT) {
        float sc = rsqrtf(rvar[c] + BN_EPS) * gamma[c];
        bnsc[c] = sc;
        bnsh[c] = (bias[c] - rmean[c]) * sc + beta[c];
    }
}

// ---- y = dinv * (x @ W^T), fp32 VALU, LDS-tiled ----------------------------
__global__ __launch_bounds__(256) void k_gemm(
        const float* __restrict__ x, const float* __restrict__ W,
        const float* __restrict__ dinv,
        float* __restrict__ y, int n) {
    __shared__ float Xs[KC * XS];
    __shared__ float Ws[KC * WS];

    int t = threadIdx.x;
    int tn = t & 7;
    int tm = t >> 3;
    int m0 = blockIdx.x * BM;

    float acc[4][8];
    #pragma unroll
    for (int i = 0; i < 4; ++i)
        #pragma unroll
        for (int j = 0; j < 8; ++j) acc[i][j] = 0.f;

    for (int ks = 0; ks < D_IN; ks += KC) {
        #pragma unroll
        for (int i = 0; i < 4; ++i) {
            int f = t + 256 * i;
            int row = f >> 3;
            int seg = f & 7;
            int gnode = m0 + row;
            if (gnode >= n) gnode = n - 1;
            floatx4 v = *(const floatx4*)(x + (size_t)gnode * D_IN + ks + seg * 4);
            #pragma unroll
            for (int j = 0; j < 4; ++j)
                Xs[(seg * 4 + j) * XS + row] = v[j];
        }
        #pragma unroll
        for (int i = 0; i < 2; ++i) {
            int f = t + 256 * i;
            int c = f >> 3;
            int seg = f & 7;
            floatx4 v = *(const floatx4*)(W + (size_t)c * D_IN + ks + seg * 4);
            #pragma unroll
            for (int j = 0; j < 4; ++j)
                Ws[(seg * 4 + j) * WS + c] = v[j];
        }
        __syncthreads();

        #pragma unroll 4
        for (int k = 0; k < KC; ++k) {
            floatx4 xv  = *(const floatx4*)&Xs[k * XS + tm * 4];
            floatx4 wv0 = *(const floatx4*)&Ws[k * WS + tn * 8];
            floatx4 wv1 = *(const floatx4*)&Ws[k * WS + tn * 8 + 4];
            #pragma unroll
            for (int i = 0; i < 4; ++i) {
                #pragma unroll
                for (int j = 0; j < 4; ++j) {
                    acc[i][j]     = fmaf(xv[i], wv0[j], acc[i][j]);
                    acc[i][j + 4] = fmaf(xv[i], wv1[j], acc[i][j + 4]);
                }
            }
        }
        __syncthreads();
    }

    #pragma unroll
    for (int i = 0; i < 4; ++i) {
        int node = m0 + tm * 4 + i;
        if (node >= n) continue;
        float dv = dinv[node];
        floatx4 o0, o1;
        #pragma unroll
        for (int j = 0; j < 4; ++j) {
            o0[j] = dv * acc[i][j];
            o1[j] = dv * acc[i][j + 4];
        }
        size_t base = (size_t)node * D_OUT + tn * 8;
        *(floatx4*)(y + base)     = o0;
        *(floatx4*)(y + base + 4) = o1;
    }
}

// ---- CSR gather-aggregate + fused BN/ReLU epilogue; ZERO atomics -----------
// One wave per node, lane = channel. out[n] = relu(bn(dinv[n]*(y[n] + sum y[src])))
__global__ __launch_bounds__(256) void k_aggregate(
        const int* __restrict__ off, const int* __restrict__ srcs,
        const float* __restrict__ y, const float* __restrict__ dinv,
        const float* __restrict__ bnsc, const float* __restrict__ bnsh,
        float* __restrict__ out, int n) {
    int node = blockIdx.x * 4 + (threadIdx.x >> 6);
    if (node >= n) return;
    int lane = threadIdx.x & 63;
    int s  = off[node];
    int e2 = off[node + 1];
    float acc = y[(size_t)node * D_OUT + lane];   // self-loop term
    int e = s;
    for (; e + 4 <= e2; e += 4) {
        int r0 = srcs[e], r1 = srcs[e + 1], r2 = srcs[e + 2], r3 = srcs[e + 3];
        float a0 = y[(size_t)r0 * D_OUT + lane];
        float a1 = y[(size_t)r1 * D_OUT + lane];
        float a2 = y[(size_t)r2 * D_OUT + lane];
        float a3 = y[(size_t)r3 * D_OUT + lane];
        acc += a0; acc += a1; acc += a2; acc += a3;
    }
    for (; e < e2; ++e)
        acc += y[(size_t)srcs[e] * D_OUT + lane];
    float v = fmaf(dinv[node] * acc, bnsc[lane], bnsh[lane]);
    out[(size_t)node * D_OUT + lane] = v > 0.f ? v : 0.f;
}

static inline char* align_up(char* p, size_t a) {
    return (char*)(((uintptr_t)p + a - 1) & ~(uintptr_t)(a - 1));
}

extern "C" void kernel_launch(void* const* d_in, const int* in_sizes, int n_in,
                              void* d_out, int out_size, void* d_ws, size_t ws_size,
                              hipStream_t stream) {
    const float* x     = (const float*)d_in[0];
    const int*   ei    = (const int*)d_in[1];
    const float* W     = (const float*)d_in[2];
    const float* bias  = (const float*)d_in[3];
    const float* gamma = (const float*)d_in[4];
    const float* beta  = (const float*)d_in[5];
    const float* rmean = (const float*)d_in[6];
    const float* rvar  = (const float*)d_in[7];
    float* out = (float*)d_out;

    int N = in_sizes[0] / D_IN;
    int E = in_sizes[1] / 2;
    int nb = (N + 1023) / 1024;           // scan blocks (<=256 for N<=262144)

    char* p = (char*)d_ws;
    int*   cnt    = (int*)p;            p += (size_t)N * 4;       p = align_up(p, 256);
    int*   off    = (int*)p;            p += (size_t)(N + 1) * 4; p = align_up(p, 256);
    int*   cur    = (int*)p;            p += (size_t)N * 4;       p = align_up(p, 256);
    int*   blksum = (int*)p;            p += 256 * 4;
    int*   blkoff = (int*)p;            p += 256 * 4;
    float* dinv   = (float*)p;          p += (size_t)N * 4;       p = align_up(p, 256);
    float* bnsc   = (float*)p;          p += D_OUT * 4;
    float* bnsh   = (float*)p;          p += D_OUT * 4;           p = align_up(p, 256);
    float* y      = (float*)p;          p += (size_t)N * D_OUT * 4; p = align_up(p, 256);
    int*   srcs   = (int*)p;

    k_zero<<<(N + 255) / 256, 256, 0, stream>>>(cnt, N);
    k_count<<<(E + 255) / 256, 256, 0, stream>>>(ei + E, cnt, E);
    k_scan1<<<nb, 256, 0, stream>>>(cnt, blksum, N);
    k_scan2<<<1, 256, 0, stream>>>(blksum, blkoff, nb);
    k_scan3<<<nb, 256, 0, stream>>>(cnt, blkoff, off, cur, dinv, N);
    k_bnparams<<<1, 64, 0, stream>>>(bias, gamma, beta, rmean, rvar, bnsc, bnsh);
    k_gemm<<<(N + BM - 1) / BM, 256, 0, stream>>>(x, W, dinv, y, N);
    k_fill<<<(E + 255) / 256, 256, 0, stream>>>(ei, cur, srcs, E);
    k_aggregate<<<(N + 3) / 4, 256, 0, stream>>>(off, srcs, y, dinv, bnsc, bnsh, out, N);
}

// Round 5
// 400.255 us; speedup vs baseline: 1.5453x; 1.2279x over previous
//
#include <hip/hip_runtime.h>

#define D_IN 256
#define D_OUT 64
#define BN_EPS 1e-5f

#define KC 32      // GEMM K-chunk
#define BM 128     // GEMM nodes per block tile
#define XS 132     // Xs row stride (floats), padded
#define WS 68      // Ws row stride (floats), padded

#define BINSHIFT 8                 // 256 nodes per bin
#define BINCAP 4608                // >= max edges per bin (mean 4092, +8 sigma)
#define PCHUNK 8192                // edges per k_part block

typedef __attribute__((ext_vector_type(4))) float floatx4;

// ---- zero counters (cnt[N] + bincur[nbins]) --------------------------------
__global__ void k_zero(int* __restrict__ p, int n) {
    int i = blockIdx.x * 256 + threadIdx.x;
    if (i < n) p[i] = 0;
}

__global__ void k_count(const int* __restrict__ col, int* __restrict__ cnt, int E) {
    int e = blockIdx.x * 256 + threadIdx.x;
    if (e < E) atomicAdd(&cnt[col[e]], 1);
}

// ---- hierarchical exclusive scan of cnt[N] -> off[N+1]; also dinv ----------
__global__ __launch_bounds__(256) void k_scan1(const int* __restrict__ cnt,
                                               int* __restrict__ blksum, int n) {
    __shared__ int ts[256];
    int b = blockIdx.x, t = threadIdx.x;
    int i0 = b * 1024 + t * 4;
    int s = 0;
    #pragma unroll
    for (int j = 0; j < 4; ++j) { int i = i0 + j; if (i < n) s += cnt[i]; }
    ts[t] = s; __syncthreads();
    for (int o = 128; o > 0; o >>= 1) {
        if (t < o) ts[t] += ts[t + o];
        __syncthreads();
    }
    if (t == 0) blksum[b] = ts[0];
}

__global__ __launch_bounds__(256) void k_scan2(const int* __restrict__ blksum,
                                               int* __restrict__ blkoff, int nb) {
    __shared__ int ts[256];
    int t = threadIdx.x;
    int own = (t < nb) ? blksum[t] : 0;
    ts[t] = own; __syncthreads();
    for (int o = 1; o < 256; o <<= 1) {
        int v = (t >= o) ? ts[t - o] : 0;
        __syncthreads();
        ts[t] += v;
        __syncthreads();
    }
    if (t < nb) blkoff[t] = ts[t] - own;
}

__global__ __launch_bounds__(256) void k_scan3(const int* __restrict__ cnt,
                                               const int* __restrict__ blkoff,
                                               int* __restrict__ off,
                                               float* __restrict__ dinv, int n) {
    __shared__ int ts[256];
    int b = blockIdx.x, t = threadIdx.x;
    int i0 = b * 1024 + t * 4;
    int c[4];
    #pragma unroll
    for (int j = 0; j < 4; ++j) { int i = i0 + j; c[j] = (i < n) ? cnt[i] : 0; }
    int tot = c[0] + c[1] + c[2] + c[3];
    ts[t] = tot; __syncthreads();
    for (int o = 1; o < 256; o <<= 1) {
        int v = (t >= o) ? ts[t - o] : 0;
        __syncthreads();
        ts[t] += v;
        __syncthreads();
    }
    int run = blkoff[b] + ts[t] - tot;
    #pragma unroll
    for (int j = 0; j < 4; ++j) {
        int i = i0 + j;
        if (i < n) {
            off[i] = run;
            dinv[i] = rsqrtf((float)(c[j] + 1));   // +1 self-loop
            run += c[j];
            if (i == n - 1) off[n] = run;
        }
    }
}

// ---- binned partition: (src,tgt) pairs into fixed-stride bin segments ------
// bin = tgt >> 8. Per-block LDS hist + one global cursor bump per (block,bin)
// -> contiguous (block,bin) runs, full-line writebacks.
__global__ __launch_bounds__(256) void k_part(
        const int* __restrict__ ei, int* __restrict__ bincur,
        int2* __restrict__ pairs, int E, int nbins) {
    __shared__ int hist[512];
    __shared__ int base[512];
    int t = threadIdx.x;
    int e0 = blockIdx.x * PCHUNK;

    for (int j = t; j < nbins; j += 256) hist[j] = 0;
    __syncthreads();

    int cols[PCHUNK / 256];
    int ranks[PCHUNK / 256];
    #pragma unroll
    for (int i = 0; i < PCHUNK / 256; ++i) {
        int e = e0 + i * 256 + t;
        if (e < E) {
            int c = ei[E + e];
            cols[i] = c;
            ranks[i] = atomicAdd(&hist[c >> BINSHIFT], 1);
        }
    }
    __syncthreads();
    for (int j = t; j < nbins; j += 256)
        base[j] = atomicAdd(&bincur[j], hist[j]);
    __syncthreads();
    #pragma unroll
    for (int i = 0; i < PCHUNK / 256; ++i) {
        int e = e0 + i * 256 + t;
        if (e < E) {
            int c = cols[i];
            int bin = c >> BINSHIFT;
            int pos = base[bin] + ranks[i];
            if (pos >= BINCAP) pos = BINCAP - 1;     // never-hit safety
            pairs[(size_t)bin * BINCAP + pos] = make_int2(ei[e], c);
        }
    }
}

// ---- per-bin CSR fill: scatter confined to the bin's ~16KB window ----------
__global__ __launch_bounds__(256) void k_fill2(
        const int2* __restrict__ pairs, const int* __restrict__ bincur,
        const int* __restrict__ off, int* __restrict__ srcs) {
    __shared__ int hist[1 << BINSHIFT];
    int bin = blockIdx.x;
    int t = threadIdx.x;
    hist[t] = 0;
    __syncthreads();
    int cnt = bincur[bin];
    const int2* bp = pairs + (size_t)bin * BINCAP;
    for (int p = t; p < cnt; p += 256) {
        int2 pr = bp[p];
        int rank = atomicAdd(&hist[pr.y & ((1 << BINSHIFT) - 1)], 1);
        srcs[off[pr.y] + rank] = pr.x;
    }
}

// ---- bn params -------------------------------------------------------------
__global__ void k_bnparams(const float* __restrict__ bias,
                           const float* __restrict__ gamma,
                           const float* __restrict__ beta,
                           const float* __restrict__ rmean,
                           const float* __restrict__ rvar,
                           float* __restrict__ bnsc, float* __restrict__ bnsh) {
    int c = threadIdx.x;
    if (c < D_OUT) {
        float sc = rsqrtf(rvar[c] + BN_EPS) * gamma[c];
        bnsc[c] = sc;
        bnsh[c] = (bias[c] - rmean[c]) * sc + beta[c];
    }
}

// ---- y = dinv * (x @ W^T), fp32 VALU, LDS-tiled ----------------------------
__global__ __launch_bounds__(256) void k_gemm(
        const float* __restrict__ x, const float* __restrict__ W,
        const float* __restrict__ dinv,
        float* __restrict__ y, int n) {
    __shared__ float Xs[KC * XS];
    __shared__ float Ws[KC * WS];

    int t = threadIdx.x;
    int tn = t & 7;
    int tm = t >> 3;
    int m0 = blockIdx.x * BM;

    float acc[4][8];
    #pragma unroll
    for (int i = 0; i < 4; ++i)
        #pragma unroll
        for (int j = 0; j < 8; ++j) acc[i][j] = 0.f;

    for (int ks = 0; ks < D_IN; ks += KC) {
        #pragma unroll
        for (int i = 0; i < 4; ++i) {
            int f = t + 256 * i;
            int row = f >> 3;
            int seg = f & 7;
            int gnode = m0 + row;
            if (gnode >= n) gnode = n - 1;
            floatx4 v = *(const floatx4*)(x + (size_t)gnode * D_IN + ks + seg * 4);
            #pragma unroll
            for (int j = 0; j < 4; ++j)
                Xs[(seg * 4 + j) * XS + row] = v[j];
        }
        #pragma unroll
        for (int i = 0; i < 2; ++i) {
            int f = t + 256 * i;
            int c = f >> 3;
            int seg = f & 7;
            floatx4 v = *(const floatx4*)(W + (size_t)c * D_IN + ks + seg * 4);
            #pragma unroll
            for (int j = 0; j < 4; ++j)
                Ws[(seg * 4 + j) * WS + c] = v[j];
        }
        __syncthreads();

        #pragma unroll 4
        for (int k = 0; k < KC; ++k) {
            floatx4 xv  = *(const floatx4*)&Xs[k * XS + tm * 4];
            floatx4 wv0 = *(const floatx4*)&Ws[k * WS + tn * 8];
            floatx4 wv1 = *(const floatx4*)&Ws[k * WS + tn * 8 + 4];
            #pragma unroll
            for (int i = 0; i < 4; ++i) {
                #pragma unroll
                for (int j = 0; j < 4; ++j) {
                    acc[i][j]     = fmaf(xv[i], wv0[j], acc[i][j]);
                    acc[i][j + 4] = fmaf(xv[i], wv1[j], acc[i][j + 4]);
                }
            }
        }
        __syncthreads();
    }

    #pragma unroll
    for (int i = 0; i < 4; ++i) {
        int node = m0 + tm * 4 + i;
        if (node >= n) continue;
        float dv = dinv[node];
        floatx4 o0, o1;
        #pragma unroll
        for (int j = 0; j < 4; ++j) {
            o0[j] = dv * acc[i][j];
            o1[j] = dv * acc[i][j + 4];
        }
        size_t base = (size_t)node * D_OUT + tn * 8;
        *(floatx4*)(y + base)     = o0;
        *(floatx4*)(y + base + 4) = o1;
    }
}

// ---- CSR gather-aggregate + fused BN/ReLU epilogue; ZERO atomics -----------
__global__ __launch_bounds__(256) void k_aggregate(
        const int* __restrict__ off, const int* __restrict__ srcs,
        const float* __restrict__ y, const float* __restrict__ dinv,
        const float* __restrict__ bnsc, const float* __restrict__ bnsh,
        float* __restrict__ out, int n) {
    int node = blockIdx.x * 4 + (threadIdx.x >> 6);
    if (node >= n) return;
    int lane = threadIdx.x & 63;
    int s  = off[node];
    int e2 = off[node + 1];
    float acc = y[(size_t)node * D_OUT + lane];   // self-loop term
    int e = s;
    for (; e + 4 <= e2; e += 4) {
        int r0 = srcs[e], r1 = srcs[e + 1], r2 = srcs[e + 2], r3 = srcs[e + 3];
        float a0 = y[(size_t)r0 * D_OUT + lane];
        float a1 = y[(size_t)r1 * D_OUT + lane];
        float a2 = y[(size_t)r2 * D_OUT + lane];
        float a3 = y[(size_t)r3 * D_OUT + lane];
        acc += a0; acc += a1; acc += a2; acc += a3;
    }
    for (; e < e2; ++e)
        acc += y[(size_t)srcs[e] * D_OUT + lane];
    float v = fmaf(dinv[node] * acc, bnsc[lane], bnsh[lane]);
    out[(size_t)node * D_OUT + lane] = v > 0.f ? v : 0.f;
}

static inline char* align_up(char* p, size_t a) {
    return (char*)(((uintptr_t)p + a - 1) & ~(uintptr_t)(a - 1));
}

extern "C" void kernel_launch(void* const* d_in, const int* in_sizes, int n_in,
                              void* d_out, int out_size, void* d_ws, size_t ws_size,
                              hipStream_t stream) {
    const float* x     = (const float*)d_in[0];
    const int*   ei    = (const int*)d_in[1];
    const float* W     = (const float*)d_in[2];
    const float* bias  = (const float*)d_in[3];
    const float* gamma = (const float*)d_in[4];
    const float* beta  = (const float*)d_in[5];
    const float* rmean = (const float*)d_in[6];
    const float* rvar  = (const float*)d_in[7];
    float* out = (float*)d_out;

    int N = in_sizes[0] / D_IN;
    int E = in_sizes[1] / 2;
    int nb = (N + 1023) / 1024;           // scan blocks
    int nbins = (N + (1 << BINSHIFT) - 1) >> BINSHIFT;   // 391 for N=100000

    char* p = (char*)d_ws;
    int*   cnt    = (int*)p;            p += (size_t)N * 4;       p = align_up(p, 256);
    int*   bincur = (int*)p;            p += (size_t)nbins * 4;   p = align_up(p, 256);
    int*   off    = (int*)p;            p += (size_t)(N + 1) * 4; p = align_up(p, 256);
    int*   blksum = (int*)p;            p += 256 * 4;
    int*   blkoff = (int*)p;            p += 256 * 4;
    float* dinv   = (float*)p;          p += (size_t)N * 4;       p = align_up(p, 256);
    float* bnsc   = (float*)p;          p += D_OUT * 4;
    float* bnsh   = (float*)p;          p += D_OUT * 4;           p = align_up(p, 256);
    float* y      = (float*)p;          p += (size_t)N * D_OUT * 4; p = align_up(p, 256);
    int*   srcs   = (int*)p;            p += (size_t)E * 4;       p = align_up(p, 256);
    int2*  pairs  = (int2*)p;           // nbins * BINCAP * 8 bytes (~14.4 MB)

    k_zero<<<(N + nbins + 255) / 256, 256, 0, stream>>>(cnt, N + nbins);  // cnt then bincur must be adjacent? no:
    // cnt and bincur are separate (aligned) — zero bincur separately:
    k_zero<<<(nbins + 255) / 256, 256, 0, stream>>>(bincur, nbins);
    k_count<<<(E + 255) / 256, 256, 0, stream>>>(ei + E, cnt, E);
    k_scan1<<<nb, 256, 0, stream>>>(cnt, blksum, N);
    k_scan2<<<1, 256, 0, stream>>>(blksum, blkoff, nb);
    k_scan3<<<nb, 256, 0, stream>>>(cnt, blkoff, off, dinv, N);
    k_bnparams<<<1, 64, 0, stream>>>(bias, gamma, beta, rmean, rvar, bnsc, bnsh);
    k_gemm<<<(N + BM - 1) / BM, 256, 0, stream>>>(x, W, dinv, y, N);
    k_part<<<(E + PCHUNK - 1) / PCHUNK, 256, 0, stream>>>(ei, bincur, pairs, E, nbins);
    k_fill2<<<nbins, 256, 0, stream>>>(pairs, bincur, off, srcs);
    k_aggregate<<<(N + 3) / 4, 256, 0, stream>>>(off, srcs, y, dinv, bnsc, bnsh, out, N);
}

// Round 6
// 385.095 us; speedup vs baseline: 1.6062x; 1.0394x over previous
//
#include <hip/hip_runtime.h>
#include <hip/hip_bf16.h>

#define D_IN 256
#define D_OUT 64
#define BN_EPS 1e-5f

#define BINSHIFT 8                 // 256 nodes per bin
#define BINCAP 4608                // >= max edges per bin (mean 4092, +8 sigma)
#define PCHUNK 8192                // edges per k_part block

typedef __attribute__((ext_vector_type(4))) float floatx4;
typedef __attribute__((ext_vector_type(8))) __bf16 bf16x8;

// ---- zero counters ---------------------------------------------------------
__global__ void k_zero(int* __restrict__ p, int n) {
    int i = blockIdx.x * 256 + threadIdx.x;
    if (i < n) p[i] = 0;
}

__global__ void k_count(const int* __restrict__ col, int* __restrict__ cnt, int E) {
    int e = blockIdx.x * 256 + threadIdx.x;
    if (e < E) atomicAdd(&cnt[col[e]], 1);
}

// ---- hierarchical exclusive scan of cnt[N] -> off[N+1]; also dinv ----------
__global__ __launch_bounds__(256) void k_scan1(const int* __restrict__ cnt,
                                               int* __restrict__ blksum, int n) {
    __shared__ int ts[256];
    int b = blockIdx.x, t = threadIdx.x;
    int i0 = b * 1024 + t * 4;
    int s = 0;
    #pragma unroll
    for (int j = 0; j < 4; ++j) { int i = i0 + j; if (i < n) s += cnt[i]; }
    ts[t] = s; __syncthreads();
    for (int o = 128; o > 0; o >>= 1) {
        if (t < o) ts[t] += ts[t + o];
        __syncthreads();
    }
    if (t == 0) blksum[b] = ts[0];
}

__global__ __launch_bounds__(256) void k_scan2(const int* __restrict__ blksum,
                                               int* __restrict__ blkoff, int nb) {
    __shared__ int ts[256];
    int t = threadIdx.x;
    int own = (t < nb) ? blksum[t] : 0;
    ts[t] = own; __syncthreads();
    for (int o = 1; o < 256; o <<= 1) {
        int v = (t >= o) ? ts[t - o] : 0;
        __syncthreads();
        ts[t] += v;
        __syncthreads();
    }
    if (t < nb) blkoff[t] = ts[t] - own;
}

__global__ __launch_bounds__(256) void k_scan3(const int* __restrict__ cnt,
                                               const int* __restrict__ blkoff,
                                               int* __restrict__ off,
                                               float* __restrict__ dinv, int n) {
    __shared__ int ts[256];
    int b = blockIdx.x, t = threadIdx.x;
    int i0 = b * 1024 + t * 4;
    int c[4];
    #pragma unroll
    for (int j = 0; j < 4; ++j) { int i = i0 + j; c[j] = (i < n) ? cnt[i] : 0; }
    int tot = c[0] + c[1] + c[2] + c[3];
    ts[t] = tot; __syncthreads();
    for (int o = 1; o < 256; o <<= 1) {
        int v = (t >= o) ? ts[t - o] : 0;
        __syncthreads();
        ts[t] += v;
        __syncthreads();
    }
    int run = blkoff[b] + ts[t] - tot;
    #pragma unroll
    for (int j = 0; j < 4; ++j) {
        int i = i0 + j;
        if (i < n) {
            off[i] = run;
            dinv[i] = rsqrtf((float)(c[j] + 1));   // +1 self-loop
            run += c[j];
            if (i == n - 1) off[n] = run;
        }
    }
}

// ---- binned partition ------------------------------------------------------
__global__ __launch_bounds__(256) void k_part(
        const int* __restrict__ ei, int* __restrict__ bincur,
        int2* __restrict__ pairs, int E, int nbins) {
    __shared__ int hist[512];
    __shared__ int base[512];
    int t = threadIdx.x;
    int e0 = blockIdx.x * PCHUNK;

    for (int j = t; j < nbins; j += 256) hist[j] = 0;
    __syncthreads();

    int cols[PCHUNK / 256];
    int ranks[PCHUNK / 256];
    #pragma unroll
    for (int i = 0; i < PCHUNK / 256; ++i) {
        int e = e0 + i * 256 + t;
        if (e < E) {
            int c = ei[E + e];
            cols[i] = c;
            ranks[i] = atomicAdd(&hist[c >> BINSHIFT], 1);
        }
    }
    __syncthreads();
    for (int j = t; j < nbins; j += 256)
        base[j] = atomicAdd(&bincur[j], hist[j]);
    __syncthreads();
    #pragma unroll
    for (int i = 0; i < PCHUNK / 256; ++i) {
        int e = e0 + i * 256 + t;
        if (e < E) {
            int c = cols[i];
            int bin = c >> BINSHIFT;
            int pos = base[bin] + ranks[i];
            if (pos >= BINCAP) pos = BINCAP - 1;     // never-hit safety
            pairs[(size_t)bin * BINCAP + pos] = make_int2(ei[e], c);
        }
    }
}

// ---- per-bin CSR fill ------------------------------------------------------
__global__ __launch_bounds__(256) void k_fill2(
        const int2* __restrict__ pairs, const int* __restrict__ bincur,
        const int* __restrict__ off, int* __restrict__ srcs) {
    __shared__ int hist[1 << BINSHIFT];
    int bin = blockIdx.x;
    int t = threadIdx.x;
    hist[t] = 0;
    __syncthreads();
    int cnt = bincur[bin];
    const int2* bp = pairs + (size_t)bin * BINCAP;
    for (int p = t; p < cnt; p += 256) {
        int2 pr = bp[p];
        int rank = atomicAdd(&hist[pr.y & ((1 << BINSHIFT) - 1)], 1);
        srcs[off[pr.y] + rank] = pr.x;
    }
}

// ---- bn params -------------------------------------------------------------
__global__ void k_bnparams(const float* __restrict__ bias,
                           const float* __restrict__ gamma,
                           const float* __restrict__ beta,
                           const float* __restrict__ rmean,
                           const float* __restrict__ rvar,
                           float* __restrict__ bnsc, float* __restrict__ bnsh) {
    int c = threadIdx.x;
    if (c < D_OUT) {
        float sc = rsqrtf(rvar[c] + BN_EPS) * gamma[c];
        bnsc[c] = sc;
        bnsh[c] = (bias[c] - rmean[c]) * sc + beta[c];
    }
}

// ---- one-time W split into bf16 hi/lo, stored in MFMA B-fragment order -----
// frag addr: ((t*8 + c)*64 + lane)*8 + j  holds W[t*16 + (lane&15)][c*32 + (lane>>4)*8 + j]
__global__ void k_wconv(const float* __restrict__ W,
                        __bf16* __restrict__ whi, __bf16* __restrict__ wlo) {
    int tid = blockIdx.x * 256 + threadIdx.x;   // 0..2047
    int lane = tid & 63, c = (tid >> 6) & 7, t = tid >> 9;
    int row = t * 16 + (lane & 15);
    int k0 = c * 32 + (lane >> 4) * 8;
    size_t dst = (size_t)tid * 8;
    #pragma unroll
    for (int j = 0; j < 8; ++j) {
        float w = W[(size_t)row * D_IN + k0 + j];
        __bf16 h = (__bf16)w;
        whi[dst + j] = h;
        wlo[dst + j] = (__bf16)(w - (float)h);
    }
}

// ---- y = dinv * (x @ W^T) via split-bf16 MFMA; no LDS ----------------------
// One wave per 16 nodes. A loaded fp32 from x, split in-register.
// err = a_lo*b_lo ~ O(1e-5): dropped.
__global__ __launch_bounds__(256) void k_gemm(
        const float* __restrict__ x, const __bf16* __restrict__ whi,
        const __bf16* __restrict__ wlo, const float* __restrict__ dinv,
        float* __restrict__ y, int n) {
    int wave = threadIdx.x >> 6;
    int lane = threadIdx.x & 63;
    int m0 = blockIdx.x * 64 + wave * 16;
    if (m0 >= n) return;
    int q = lane >> 4, cl = lane & 15;
    int arow = m0 + cl; if (arow >= n) arow = n - 1;   // clamp (tail rows unused)
    const float* ap = x + (size_t)arow * D_IN + q * 8;

    floatx4 acc[4] = {{0.f,0.f,0.f,0.f},{0.f,0.f,0.f,0.f},
                      {0.f,0.f,0.f,0.f},{0.f,0.f,0.f,0.f}};

    #pragma unroll
    for (int c = 0; c < 8; ++c) {
        floatx4 a0 = *(const floatx4*)(ap + c * 32);
        floatx4 a1 = *(const floatx4*)(ap + c * 32 + 4);
        bf16x8 ahi, alo;
        #pragma unroll
        for (int j = 0; j < 4; ++j) {
            __bf16 h0 = (__bf16)a0[j];
            __bf16 h1 = (__bf16)a1[j];
            ahi[j] = h0;     alo[j] = (__bf16)(a0[j] - (float)h0);
            ahi[4 + j] = h1; alo[4 + j] = (__bf16)(a1[j] - (float)h1);
        }
        #pragma unroll
        for (int t = 0; t < 4; ++t) {
            size_t fo = ((size_t)(t * 8 + c) * 64 + lane) * 8;
            bf16x8 bh = *(const bf16x8*)(whi + fo);
            bf16x8 bl = *(const bf16x8*)(wlo + fo);
            acc[t] = __builtin_amdgcn_mfma_f32_16x16x32_bf16(ahi, bh, acc[t], 0, 0, 0);
            acc[t] = __builtin_amdgcn_mfma_f32_16x16x32_bf16(alo, bh, acc[t], 0, 0, 0);
            acc[t] = __builtin_amdgcn_mfma_f32_16x16x32_bf16(ahi, bl, acc[t], 0, 0, 0);
        }
    }

    int nb = m0 + q * 4;
    float dv[4];
    #pragma unroll
    for (int r = 0; r < 4; ++r) dv[r] = (nb + r < n) ? dinv[nb + r] : 0.f;
    #pragma unroll
    for (int t = 0; t < 4; ++t) {
        #pragma unroll
        for (int r = 0; r < 4; ++r) {
            int node = nb + r;
            if (node < n)
                y[(size_t)node * D_OUT + t * 16 + cl] = dv[r] * acc[t][r];
        }
    }
}

// ---- CSR gather-aggregate + fused BN/ReLU epilogue; ZERO atomics -----------
__global__ __launch_bounds__(256) void k_aggregate(
        const int* __restrict__ off, const int* __restrict__ srcs,
        const float* __restrict__ y, const float* __restrict__ dinv,
        const float* __restrict__ bnsc, const float* __restrict__ bnsh,
        float* __restrict__ out, int n) {
    int node = blockIdx.x * 4 + (threadIdx.x >> 6);
    if (node >= n) return;
    int lane = threadIdx.x & 63;
    int s  = off[node];
    int e2 = off[node + 1];
    float acc = y[(size_t)node * D_OUT + lane];   // self-loop term
    int e = s;
    for (; e + 4 <= e2; e += 4) {
        int r0 = srcs[e], r1 = srcs[e + 1], r2 = srcs[e + 2], r3 = srcs[e + 3];
        float a0 = y[(size_t)r0 * D_OUT + lane];
        float a1 = y[(size_t)r1 * D_OUT + lane];
        float a2 = y[(size_t)r2 * D_OUT + lane];
        float a3 = y[(size_t)r3 * D_OUT + lane];
        acc += a0; acc += a1; acc += a2; acc += a3;
    }
    for (; e < e2; ++e)
        acc += y[(size_t)srcs[e] * D_OUT + lane];
    float v = fmaf(dinv[node] * acc, bnsc[lane], bnsh[lane]);
    out[(size_t)node * D_OUT + lane] = v > 0.f ? v : 0.f;
}

static inline char* align_up(char* p, size_t a) {
    return (char*)(((uintptr_t)p + a - 1) & ~(uintptr_t)(a - 1));
}

extern "C" void kernel_launch(void* const* d_in, const int* in_sizes, int n_in,
                              void* d_out, int out_size, void* d_ws, size_t ws_size,
                              hipStream_t stream) {
    const float* x     = (const float*)d_in[0];
    const int*   ei    = (const int*)d_in[1];
    const float* W     = (const float*)d_in[2];
    const float* bias  = (const float*)d_in[3];
    const float* gamma = (const float*)d_in[4];
    const float* beta  = (const float*)d_in[5];
    const float* rmean = (const float*)d_in[6];
    const float* rvar  = (const float*)d_in[7];
    float* out = (float*)d_out;

    int N = in_sizes[0] / D_IN;
    int E = in_sizes[1] / 2;
    int nb = (N + 1023) / 1024;           // scan blocks
    int nbins = (N + (1 << BINSHIFT) - 1) >> BINSHIFT;   // 391 for N=100000

    char* p = (char*)d_ws;
    int*    cnt    = (int*)p;           p += (size_t)N * 4;       p = align_up(p, 256);
    int*    bincur = (int*)p;           p += (size_t)nbins * 4;   p = align_up(p, 256);
    int*    off    = (int*)p;           p += (size_t)(N + 1) * 4; p = align_up(p, 256);
    int*    blksum = (int*)p;           p += 256 * 4;
    int*    blkoff = (int*)p;           p += 256 * 4;
    float*  dinv   = (float*)p;         p += (size_t)N * 4;       p = align_up(p, 256);
    float*  bnsc   = (float*)p;         p += D_OUT * 4;
    float*  bnsh   = (float*)p;         p += D_OUT * 4;           p = align_up(p, 256);
    __bf16* whi    = (__bf16*)p;        p += (size_t)D_OUT * D_IN * 2; p = align_up(p, 256);
    __bf16* wlo    = (__bf16*)p;        p += (size_t)D_OUT * D_IN * 2; p = align_up(p, 256);
    float*  y      = (float*)p;         p += (size_t)N * D_OUT * 4;    p = align_up(p, 256);
    int*    srcs   = (int*)p;           p += (size_t)E * 4;       p = align_up(p, 256);
    int2*   pairs  = (int2*)p;          // nbins * BINCAP * 8 bytes (~14.4 MB)

    k_zero<<<(N + 255) / 256, 256, 0, stream>>>(cnt, N);
    k_zero<<<(nbins + 255) / 256, 256, 0, stream>>>(bincur, nbins);
    k_count<<<(E + 255) / 256, 256, 0, stream>>>(ei + E, cnt, E);
    k_scan1<<<nb, 256, 0, stream>>>(cnt, blksum, N);
    k_scan2<<<1, 256, 0, stream>>>(blksum, blkoff, nb);
    k_scan3<<<nb, 256, 0, stream>>>(cnt, blkoff, off, dinv, N);
    k_bnparams<<<1, 64, 0, stream>>>(bias, gamma, beta, rmean, rvar, bnsc, bnsh);
    k_wconv<<<8, 256, 0, stream>>>(W, whi, wlo);
    k_gemm<<<(N + 63) / 64, 256, 0, stream>>>(x, whi, wlo, dinv, y, N);
    k_part<<<(E + PCHUNK - 1) / PCHUNK, 256, 0, stream>>>(ei, bincur, pairs, E, nbins);
    k_fill2<<<nbins, 256, 0, stream>>>(pairs, bincur, off, srcs);
    k_aggregate<<<(N + 3) / 4, 256, 0, stream>>>(off, srcs, y, dinv, bnsc, bnsh, out, N);
}

// Round 7
// 300.190 us; speedup vs baseline: 2.0604x; 1.2828x over previous
//
#include <hip/hip_runtime.h>
#include <hip/hip_bf16.h>

#define D_IN 256
#define D_OUT 64
#define BN_EPS 1e-5f

#define BINSHIFT 8                 // 256 nodes per bin
#define BINCAP 4608                // >= max edges per bin (mean 4092, +8 sigma)
#define PCHUNK 8192                // edges per k_part block

typedef __attribute__((ext_vector_type(4))) float floatx4;
typedef __attribute__((ext_vector_type(8))) __bf16 bf16x8;

// ---- prep: zero bincur + bn params + W split (MFMA B-fragment order) -------
// grid 10 x 256: b0,b1 -> bincur zero (b1 also bnparams); b2..9 -> wconv
__global__ __launch_bounds__(256) void k_prep(
        const float* __restrict__ W, __bf16* __restrict__ whi, __bf16* __restrict__ wlo,
        const float* __restrict__ bias, const float* __restrict__ gamma,
        const float* __restrict__ beta, const float* __restrict__ rmean,
        const float* __restrict__ rvar,
        float* __restrict__ bnsc, float* __restrict__ bnsh,
        int* __restrict__ bincur, int nbins) {
    int b = blockIdx.x, t = threadIdx.x;
    if (b < 2) {
        int i = b * 256 + t;
        if (i < nbins) bincur[i] = 0;
        if (b == 1 && t < D_OUT) {
            float sc = rsqrtf(rvar[t] + BN_EPS) * gamma[t];
            bnsc[t] = sc;
            bnsh[t] = (bias[t] - rmean[t]) * sc + beta[t];
        }
        return;
    }
    int tid = (b - 2) * 256 + t;   // 0..2047
    int lane = tid & 63, c = (tid >> 6) & 7, tt = tid >> 9;
    int row = tt * 16 + (lane & 15);
    int k0 = c * 32 + (lane >> 4) * 8;
    size_t dst = (size_t)tid * 8;
    #pragma unroll
    for (int j = 0; j < 8; ++j) {
        float w = W[(size_t)row * D_IN + k0 + j];
        __bf16 h = (__bf16)w;
        whi[dst + j] = h;
        wlo[dst + j] = (__bf16)(w - (float)h);
    }
}

// ---- binned partition: packed (src<<8 | tgt&255) into bin segments ---------
__global__ __launch_bounds__(256) void k_part(
        const int* __restrict__ ei, int* __restrict__ bincur,
        unsigned* __restrict__ pairs, int E, int nbins) {
    __shared__ int hist[512];
    __shared__ int base[512];
    int t = threadIdx.x;
    int e0 = blockIdx.x * PCHUNK;

    for (int j = t; j < nbins; j += 256) hist[j] = 0;
    __syncthreads();

    int cols[PCHUNK / 256];
    int ranks[PCHUNK / 256];
    #pragma unroll
    for (int i = 0; i < PCHUNK / 256; ++i) {
        int e = e0 + i * 256 + t;
        if (e < E) {
            int c = ei[E + e];
            cols[i] = c;
            ranks[i] = atomicAdd(&hist[c >> BINSHIFT], 1);
        }
    }
    __syncthreads();
    for (int j = t; j < nbins; j += 256)
        base[j] = atomicAdd(&bincur[j], hist[j]);
    __syncthreads();
    #pragma unroll
    for (int i = 0; i < PCHUNK / 256; ++i) {
        int e = e0 + i * 256 + t;
        if (e < E) {
            int c = cols[i];
            int bin = c >> BINSHIFT;
            int pos = base[bin] + ranks[i];
            if (pos >= BINCAP) pos = BINCAP - 1;     // never-hit safety
            pairs[(size_t)bin * BINCAP + pos] =
                ((unsigned)ei[e] << 8) | (unsigned)(c & 255);
        }
    }
}

// ---- scan of 391 bin counts -> binoff; off[N] = E ---------------------------
__global__ __launch_bounds__(256) void k_binscan(
        const int* __restrict__ bincur, int* __restrict__ binoff,
        int* __restrict__ off, int nbins, int N) {
    __shared__ int sc[256];
    int t = threadIdx.x;
    int i0 = 2 * t, i1 = 2 * t + 1;
    int v0 = (i0 < nbins) ? bincur[i0] : 0;
    int v1 = (i1 < nbins) ? bincur[i1] : 0;
    int s = v0 + v1;
    sc[t] = s;
    __syncthreads();
    for (int o = 1; o < 256; o <<= 1) {
        int v = (t >= o) ? sc[t - o] : 0;
        __syncthreads();
        sc[t] += v;
        __syncthreads();
    }
    int excl = sc[t] - s;
    if (i0 < nbins) binoff[i0] = excl;
    if (i1 < nbins) binoff[i1] = excl + v0;
    if (t == 255) off[N] = sc[255];
}

// ---- per-bin: node counts -> off/dinv (local scan) -> CSR scatter ----------
__global__ __launch_bounds__(256) void k_fill3(
        const unsigned* __restrict__ pairs, const int* __restrict__ bincur,
        const int* __restrict__ binoff, int* __restrict__ off,
        float* __restrict__ dinv, int* __restrict__ srcs, int n) {
    __shared__ int hist[256];
    __shared__ int sc[256];
    __shared__ int curs[256];
    int bin = blockIdx.x, t = threadIdx.x;
    hist[t] = 0;
    __syncthreads();
    int cnt = bincur[bin];
    const unsigned* bp = pairs + (size_t)bin * BINCAP;
    for (int p = t; p < cnt; p += 256)
        atomicAdd(&hist[bp[p] & 255u], 1);
    __syncthreads();
    int own = hist[t];
    sc[t] = own;
    __syncthreads();
    for (int o = 1; o < 256; o <<= 1) {
        int v = (t >= o) ? sc[t - o] : 0;
        __syncthreads();
        sc[t] += v;
        __syncthreads();
    }
    int base = binoff[bin] + sc[t] - own;
    int node = (bin << BINSHIFT) + t;
    curs[t] = base;
    if (node < n) {
        off[node] = base;
        dinv[node] = rsqrtf((float)(own + 1));   // +1 self-loop
    }
    __syncthreads();
    for (int p = t; p < cnt; p += 256) {
        unsigned v = bp[p];
        int pos = atomicAdd(&curs[v & 255u], 1);
        srcs[pos] = (int)(v >> 8);
    }
}

// ---- y(bf16) = dinv * (x @ W^T) via split-bf16 MFMA; no LDS ----------------
__global__ __launch_bounds__(256) void k_gemm(
        const float* __restrict__ x, const __bf16* __restrict__ whi,
        const __bf16* __restrict__ wlo, const float* __restrict__ dinv,
        __bf16* __restrict__ yb, int n) {
    int wave = threadIdx.x >> 6;
    int lane = threadIdx.x & 63;
    int m0 = blockIdx.x * 64 + wave * 16;
    if (m0 >= n) return;
    int q = lane >> 4, cl = lane & 15;
    int arow = m0 + cl; if (arow >= n) arow = n - 1;   // clamp (tail rows unused)
    const float* ap = x + (size_t)arow * D_IN + q * 8;

    floatx4 acc[4] = {{0.f,0.f,0.f,0.f},{0.f,0.f,0.f,0.f},
                      {0.f,0.f,0.f,0.f},{0.f,0.f,0.f,0.f}};

    #pragma unroll
    for (int c = 0; c < 8; ++c) {
        floatx4 a0 = *(const floatx4*)(ap + c * 32);
        floatx4 a1 = *(const floatx4*)(ap + c * 32 + 4);
        bf16x8 ahi, alo;
        #pragma unroll
        for (int j = 0; j < 4; ++j) {
            __bf16 h0 = (__bf16)a0[j];
            __bf16 h1 = (__bf16)a1[j];
            ahi[j] = h0;     alo[j] = (__bf16)(a0[j] - (float)h0);
            ahi[4 + j] = h1; alo[4 + j] = (__bf16)(a1[j] - (float)h1);
        }
        #pragma unroll
        for (int t = 0; t < 4; ++t) {
            size_t fo = ((size_t)(t * 8 + c) * 64 + lane) * 8;
            bf16x8 bh = *(const bf16x8*)(whi + fo);
            bf16x8 bl = *(const bf16x8*)(wlo + fo);
            acc[t] = __builtin_amdgcn_mfma_f32_16x16x32_bf16(ahi, bh, acc[t], 0, 0, 0);
            acc[t] = __builtin_amdgcn_mfma_f32_16x16x32_bf16(alo, bh, acc[t], 0, 0, 0);
            acc[t] = __builtin_amdgcn_mfma_f32_16x16x32_bf16(ahi, bl, acc[t], 0, 0, 0);
        }
    }

    int nb = m0 + q * 4;
    float dv[4];
    #pragma unroll
    for (int r = 0; r < 4; ++r) dv[r] = (nb + r < n) ? dinv[nb + r] : 0.f;
    #pragma unroll
    for (int t = 0; t < 4; ++t) {
        #pragma unroll
        for (int r = 0; r < 4; ++r) {
            int node = nb + r;
            if (node < n)
                yb[(size_t)node * D_OUT + t * 16 + cl] = (__bf16)(dv[r] * acc[t][r]);
        }
    }
}

// ---- CSR gather-aggregate (bf16 y, 2 edges/wave) + fused BN/ReLU -----------
// Wave per node; half-wave per edge; lane covers 2 channels (4B loads).
__global__ __launch_bounds__(256) void k_aggregate(
        const int* __restrict__ off, const int* __restrict__ srcs,
        const unsigned* __restrict__ ybf, const float* __restrict__ dinv,
        const float* __restrict__ bnsc, const float* __restrict__ bnsh,
        float* __restrict__ out, int n) {
    int node = blockIdx.x * 4 + (threadIdx.x >> 6);
    if (node >= n) return;
    int lane = threadIdx.x & 63;
    int half = lane >> 5, sl = lane & 31;
    int s = off[node], e2 = off[node + 1];
    float a0 = 0.f, a1 = 0.f;
    if (half == 0) {                             // self-loop term, counted once
        unsigned v = ybf[(size_t)node * 32 + sl];
        a0 += __uint_as_float(v << 16);
        a1 += __uint_as_float(v & 0xffff0000u);
    }
    int e = s + half;
    for (; e + 2 < e2; e += 4) {
        int r0 = srcs[e], r1 = srcs[e + 2];
        unsigned v0 = ybf[(size_t)r0 * 32 + sl];
        unsigned v1 = ybf[(size_t)r1 * 32 + sl];
        a0 += __uint_as_float(v0 << 16);
        a1 += __uint_as_float(v0 & 0xffff0000u);
        a0 += __uint_as_float(v1 << 16);
        a1 += __uint_as_float(v1 & 0xffff0000u);
    }
    if (e < e2) {
        unsigned v = ybf[(size_t)srcs[e] * 32 + sl];
        a0 += __uint_as_float(v << 16);
        a1 += __uint_as_float(v & 0xffff0000u);
    }
    a0 += __shfl_xor(a0, 32);
    a1 += __shfl_xor(a1, 32);
    if (half == 0) {
        float dv = dinv[node];
        int c = sl * 2;
        float o0 = fmaf(dv * a0, bnsc[c],     bnsh[c]);
        float o1 = fmaf(dv * a1, bnsc[c + 1], bnsh[c + 1]);
        o0 = o0 > 0.f ? o0 : 0.f;
        o1 = o1 > 0.f ? o1 : 0.f;
        *(float2*)(out + (size_t)node * D_OUT + c) = make_float2(o0, o1);
    }
}

static inline char* align_up(char* p, size_t a) {
    return (char*)(((uintptr_t)p + a - 1) & ~(uintptr_t)(a - 1));
}

extern "C" void kernel_launch(void* const* d_in, const int* in_sizes, int n_in,
                              void* d_out, int out_size, void* d_ws, size_t ws_size,
                              hipStream_t stream) {
    const float* x     = (const float*)d_in[0];
    const int*   ei    = (const int*)d_in[1];
    const float* W     = (const float*)d_in[2];
    const float* bias  = (const float*)d_in[3];
    const float* gamma = (const float*)d_in[4];
    const float* beta  = (const float*)d_in[5];
    const float* rmean = (const float*)d_in[6];
    const float* rvar  = (const float*)d_in[7];
    float* out = (float*)d_out;

    int N = in_sizes[0] / D_IN;
    int E = in_sizes[1] / 2;
    int nbins = (N + (1 << BINSHIFT) - 1) >> BINSHIFT;   // 391 for N=100000

    char* p = (char*)d_ws;
    int*      bincur = (int*)p;         p += 512 * 4;
    int*      binoff = (int*)p;         p += 512 * 4;
    int*      off    = (int*)p;         p += (size_t)(N + 1) * 4; p = align_up(p, 256);
    float*    dinv   = (float*)p;       p += (size_t)N * 4;       p = align_up(p, 256);
    float*    bnsc   = (float*)p;       p += D_OUT * 4;
    float*    bnsh   = (float*)p;       p += D_OUT * 4;           p = align_up(p, 256);
    __bf16*   whi    = (__bf16*)p;      p += (size_t)D_OUT * D_IN * 2; p = align_up(p, 256);
    __bf16*   wlo    = (__bf16*)p;      p += (size_t)D_OUT * D_IN * 2; p = align_up(p, 256);
    __bf16*   yb     = (__bf16*)p;      p += (size_t)N * D_OUT * 2;    p = align_up(p, 256);
    int*      srcs   = (int*)p;         p += (size_t)E * 4;       p = align_up(p, 256);
    unsigned* pairs  = (unsigned*)p;    // nbins * BINCAP * 4 bytes (~7.2 MB)

    k_prep<<<10, 256, 0, stream>>>(W, whi, wlo, bias, gamma, beta, rmean, rvar,
                                   bnsc, bnsh, bincur, nbins);
    k_part<<<(E + PCHUNK - 1) / PCHUNK, 256, 0, stream>>>(ei, bincur, pairs, E, nbins);
    k_binscan<<<1, 256, 0, stream>>>(bincur, binoff, off, nbins, N);
    k_fill3<<<nbins, 256, 0, stream>>>(pairs, bincur, binoff, off, dinv, srcs, N);
    k_gemm<<<(N + 63) / 64, 256, 0, stream>>>(x, whi, wlo, dinv, yb, N);
    k_aggregate<<<(N + 3) / 4, 256, 0, stream>>>(off, srcs, (const unsigned*)yb,
                                                 dinv, bnsc, bnsh, out, N);
}

// Round 8
// 283.453 us; speedup vs baseline: 2.1821x; 1.0590x over previous
//
#include <hip/hip_runtime.h>
#include <hip/hip_bf16.h>

#define D_IN 256
#define D_OUT 64
#define BN_EPS 1e-5f

#define BINSHIFT 8                 // 256 nodes per bin
#define BINCAP 4608                // >= max edges per bin (mean 4092, +8 sigma)
#define PCHUNK 8192                // edges per k_part block

typedef __attribute__((ext_vector_type(4))) float floatx4;
typedef __attribute__((ext_vector_type(8))) __bf16 bf16x8;

// ---- prep: zero bincur + bn params + W split (MFMA B-fragment order) -------
__global__ __launch_bounds__(256) void k_prep(
        const float* __restrict__ W, __bf16* __restrict__ whi, __bf16* __restrict__ wlo,
        const float* __restrict__ bias, const float* __restrict__ gamma,
        const float* __restrict__ beta, const float* __restrict__ rmean,
        const float* __restrict__ rvar,
        float* __restrict__ bnsc, float* __restrict__ bnsh,
        int* __restrict__ bincur, int nbins) {
    int b = blockIdx.x, t = threadIdx.x;
    if (b < 2) {
        int i = b * 256 + t;
        if (i < nbins) bincur[i] = 0;
        if (b == 1 && t < D_OUT) {
            float sc = rsqrtf(rvar[t] + BN_EPS) * gamma[t];
            bnsc[t] = sc;
            bnsh[t] = (bias[t] - rmean[t]) * sc + beta[t];
        }
        return;
    }
    int tid = (b - 2) * 256 + t;   // 0..2047
    int lane = tid & 63, c = (tid >> 6) & 7, tt = tid >> 9;
    int row = tt * 16 + (lane & 15);
    int k0 = c * 32 + (lane >> 4) * 8;
    size_t dst = (size_t)tid * 8;
    #pragma unroll
    for (int j = 0; j < 8; ++j) {
        float w = W[(size_t)row * D_IN + k0 + j];
        __bf16 h = (__bf16)w;
        whi[dst + j] = h;
        wlo[dst + j] = (__bf16)(w - (float)h);
    }
}

// ---- binned partition: packed (src<<8 | tgt&255) into bin segments ---------
__global__ __launch_bounds__(256) void k_part(
        const int* __restrict__ ei, int* __restrict__ bincur,
        unsigned* __restrict__ pairs, int E, int nbins) {
    __shared__ int hist[512];
    __shared__ int base[512];
    int t = threadIdx.x;
    int e0 = blockIdx.x * PCHUNK;

    for (int j = t; j < nbins; j += 256) hist[j] = 0;
    __syncthreads();

    int cols[PCHUNK / 256];
    int ranks[PCHUNK / 256];
    #pragma unroll
    for (int i = 0; i < PCHUNK / 256; ++i) {
        int e = e0 + i * 256 + t;
        if (e < E) {
            int c = ei[E + e];
            cols[i] = c;
            ranks[i] = atomicAdd(&hist[c >> BINSHIFT], 1);
        }
    }
    __syncthreads();
    for (int j = t; j < nbins; j += 256)
        base[j] = atomicAdd(&bincur[j], hist[j]);
    __syncthreads();
    #pragma unroll
    for (int i = 0; i < PCHUNK / 256; ++i) {
        int e = e0 + i * 256 + t;
        if (e < E) {
            int c = cols[i];
            int bin = c >> BINSHIFT;
            int pos = base[bin] + ranks[i];
            if (pos >= BINCAP) pos = BINCAP - 1;     // never-hit safety
            pairs[(size_t)bin * BINCAP + pos] =
                ((unsigned)ei[e] << 8) | (unsigned)(c & 255);
        }
    }
}

// ---- scan of bin counts -> binoff; off[N] = E --------------------------------
__global__ __launch_bounds__(256) void k_binscan(
        const int* __restrict__ bincur, int* __restrict__ binoff,
        int* __restrict__ off, int nbins, int N) {
    __shared__ int sc[256];
    int t = threadIdx.x;
    int i0 = 2 * t, i1 = 2 * t + 1;
    int v0 = (i0 < nbins) ? bincur[i0] : 0;
    int v1 = (i1 < nbins) ? bincur[i1] : 0;
    int s = v0 + v1;
    sc[t] = s;
    __syncthreads();
    for (int o = 1; o < 256; o <<= 1) {
        int v = (t >= o) ? sc[t - o] : 0;
        __syncthreads();
        sc[t] += v;
        __syncthreads();
    }
    int excl = sc[t] - s;
    if (i0 < nbins) binoff[i0] = excl;
    if (i1 < nbins) binoff[i1] = excl + v0;
    if (t == 255) off[N] = sc[255];
}

// ---- per-bin: node counts -> off/dinv (local scan) -> CSR scatter ----------
__global__ __launch_bounds__(256) void k_fill3(
        const unsigned* __restrict__ pairs, const int* __restrict__ bincur,
        const int* __restrict__ binoff, int* __restrict__ off,
        float* __restrict__ dinv, int* __restrict__ srcs, int n) {
    __shared__ int hist[256];
    __shared__ int sc[256];
    __shared__ int curs[256];
    int bin = blockIdx.x, t = threadIdx.x;
    hist[t] = 0;
    __syncthreads();
    int cnt = bincur[bin];
    const unsigned* bp = pairs + (size_t)bin * BINCAP;
    for (int p = t; p < cnt; p += 256)
        atomicAdd(&hist[bp[p] & 255u], 1);
    __syncthreads();
    int own = hist[t];
    sc[t] = own;
    __syncthreads();
    for (int o = 1; o < 256; o <<= 1) {
        int v = (t >= o) ? sc[t - o] : 0;
        __syncthreads();
        sc[t] += v;
        __syncthreads();
    }
    int base = binoff[bin] + sc[t] - own;
    int node = (bin << BINSHIFT) + t;
    curs[t] = base;
    if (node < n) {
        off[node] = base;
        dinv[node] = rsqrtf((float)(own + 1));   // +1 self-loop
    }
    __syncthreads();
    for (int p = t; p < cnt; p += 256) {
        unsigned v = bp[p];
        int pos = atomicAdd(&curs[v & 255u], 1);
        srcs[pos] = (int)(v >> 8);
    }
}

// ---- y(bf16) = dinv * (x @ W^T) via split-bf16 MFMA; no LDS ----------------
__global__ __launch_bounds__(256) void k_gemm(
        const float* __restrict__ x, const __bf16* __restrict__ whi,
        const __bf16* __restrict__ wlo, const float* __restrict__ dinv,
        __bf16* __restrict__ yb, int n) {
    int wave = threadIdx.x >> 6;
    int lane = threadIdx.x & 63;
    int m0 = blockIdx.x * 64 + wave * 16;
    if (m0 >= n) return;
    int q = lane >> 4, cl = lane & 15;
    int arow = m0 + cl; if (arow >= n) arow = n - 1;   // clamp (tail rows unused)
    const float* ap = x + (size_t)arow * D_IN + q * 8;

    floatx4 acc[4] = {{0.f,0.f,0.f,0.f},{0.f,0.f,0.f,0.f},
                      {0.f,0.f,0.f,0.f},{0.f,0.f,0.f,0.f}};

    #pragma unroll
    for (int c = 0; c < 8; ++c) {
        floatx4 a0 = *(const floatx4*)(ap + c * 32);
        floatx4 a1 = *(const floatx4*)(ap + c * 32 + 4);
        bf16x8 ahi, alo;
        #pragma unroll
        for (int j = 0; j < 4; ++j) {
            __bf16 h0 = (__bf16)a0[j];
            __bf16 h1 = (__bf16)a1[j];
            ahi[j] = h0;     alo[j] = (__bf16)(a0[j] - (float)h0);
            ahi[4 + j] = h1; alo[4 + j] = (__bf16)(a1[j] - (float)h1);
        }
        #pragma unroll
        for (int t = 0; t < 4; ++t) {
            size_t fo = ((size_t)(t * 8 + c) * 64 + lane) * 8;
            bf16x8 bh = *(const bf16x8*)(whi + fo);
            bf16x8 bl = *(const bf16x8*)(wlo + fo);
            acc[t] = __builtin_amdgcn_mfma_f32_16x16x32_bf16(ahi, bh, acc[t], 0, 0, 0);
            acc[t] = __builtin_amdgcn_mfma_f32_16x16x32_bf16(alo, bh, acc[t], 0, 0, 0);
            acc[t] = __builtin_amdgcn_mfma_f32_16x16x32_bf16(ahi, bl, acc[t], 0, 0, 0);
        }
    }

    int nb = m0 + q * 4;
    float dv[4];
    #pragma unroll
    for (int r = 0; r < 4; ++r) dv[r] = (nb + r < n) ? dinv[nb + r] : 0.f;
    #pragma unroll
    for (int t = 0; t < 4; ++t) {
        #pragma unroll
        for (int r = 0; r < 4; ++r) {
            int node = nb + r;
            if (node < n)
                yb[(size_t)node * D_OUT + t * 16 + cl] = (__bf16)(dv[r] * acc[t][r]);
        }
    }
}

// ---- CSR gather-aggregate: quarter-wave per edge, 16 rows in flight --------
// Wave per node; quarter (16 lanes) per edge; lane = 4 channels (uint2 = 8B).
__device__ __forceinline__ void acc_row(uint2 v, float& a0, float& a1,
                                        float& a2, float& a3) {
    a0 += __uint_as_float(v.x << 16);
    a1 += __uint_as_float(v.x & 0xffff0000u);
    a2 += __uint_as_float(v.y << 16);
    a3 += __uint_as_float(v.y & 0xffff0000u);
}

__global__ __launch_bounds__(256) void k_aggregate(
        const int* __restrict__ off, const int* __restrict__ srcs,
        const unsigned* __restrict__ ybf, const float* __restrict__ dinv,
        const float* __restrict__ bnsc, const float* __restrict__ bnsh,
        float* __restrict__ out, int n) {
    int node = blockIdx.x * 4 + (threadIdx.x >> 6);
    if (node >= n) return;
    int lane = threadIdx.x & 63;
    int q = lane >> 4, sl = lane & 15;      // quarter, sub-lane
    int s = off[node], e2 = off[node + 1];

    float a0 = 0.f, a1 = 0.f, a2 = 0.f, a3 = 0.f;
    float dv = 0.f;
    floatx4 bs, bh;
    if (q == 0) {                            // self-loop + epilogue params
        dv = dinv[node];
        bs = *(const floatx4*)(bnsc + sl * 4);
        bh = *(const floatx4*)(bnsh + sl * 4);
        uint2 v = *(const uint2*)(ybf + (size_t)node * 32 + sl * 2);
        acc_row(v, a0, a1, a2, a3);
    }

    int e = s + q;
    for (; e + 12 < e2; e += 16) {           // 4 rows in flight per quarter
        int r0 = srcs[e], r1 = srcs[e + 4], r2 = srcs[e + 8], r3 = srcs[e + 12];
        uint2 v0 = *(const uint2*)(ybf + (size_t)r0 * 32 + sl * 2);
        uint2 v1 = *(const uint2*)(ybf + (size_t)r1 * 32 + sl * 2);
        uint2 v2 = *(const uint2*)(ybf + (size_t)r2 * 32 + sl * 2);
        uint2 v3 = *(const uint2*)(ybf + (size_t)r3 * 32 + sl * 2);
        acc_row(v0, a0, a1, a2, a3);
        acc_row(v1, a0, a1, a2, a3);
        acc_row(v2, a0, a1, a2, a3);
        acc_row(v3, a0, a1, a2, a3);
    }
    for (; e + 4 < e2; e += 8) {
        int r0 = srcs[e], r1 = srcs[e + 4];
        uint2 v0 = *(const uint2*)(ybf + (size_t)r0 * 32 + sl * 2);
        uint2 v1 = *(const uint2*)(ybf + (size_t)r1 * 32 + sl * 2);
        acc_row(v0, a0, a1, a2, a3);
        acc_row(v1, a0, a1, a2, a3);
    }
    for (; e < e2; e += 4) {
        uint2 v = *(const uint2*)(ybf + (size_t)srcs[e] * 32 + sl * 2);
        acc_row(v, a0, a1, a2, a3);
    }

    a0 += __shfl_xor(a0, 16); a1 += __shfl_xor(a1, 16);
    a2 += __shfl_xor(a2, 16); a3 += __shfl_xor(a3, 16);
    a0 += __shfl_xor(a0, 32); a1 += __shfl_xor(a1, 32);
    a2 += __shfl_xor(a2, 32); a3 += __shfl_xor(a3, 32);

    if (q == 0) {
        float o0 = fmaf(dv * a0, bs[0], bh[0]);
        float o1 = fmaf(dv * a1, bs[1], bh[1]);
        float o2 = fmaf(dv * a2, bs[2], bh[2]);
        float o3 = fmaf(dv * a3, bs[3], bh[3]);
        floatx4 o = { o0 > 0.f ? o0 : 0.f, o1 > 0.f ? o1 : 0.f,
                      o2 > 0.f ? o2 : 0.f, o3 > 0.f ? o3 : 0.f };
        *(floatx4*)(out + (size_t)node * D_OUT + sl * 4) = o;
    }
}

static inline char* align_up(char* p, size_t a) {
    return (char*)(((uintptr_t)p + a - 1) & ~(uintptr_t)(a - 1));
}

extern "C" void kernel_launch(void* const* d_in, const int* in_sizes, int n_in,
                              void* d_out, int out_size, void* d_ws, size_t ws_size,
                              hipStream_t stream) {
    const float* x     = (const float*)d_in[0];
    const int*   ei    = (const int*)d_in[1];
    const float* W     = (const float*)d_in[2];
    const float* bias  = (const float*)d_in[3];
    const float* gamma = (const float*)d_in[4];
    const float* beta  = (const float*)d_in[5];
    const float* rmean = (const float*)d_in[6];
    const float* rvar  = (const float*)d_in[7];
    float* out = (float*)d_out;

    int N = in_sizes[0] / D_IN;
    int E = in_sizes[1] / 2;
    int nbins = (N + (1 << BINSHIFT) - 1) >> BINSHIFT;   // 391 for N=100000

    char* p = (char*)d_ws;
    int*      bincur = (int*)p;         p += 512 * 4;
    int*      binoff = (int*)p;         p += 512 * 4;
    int*      off    = (int*)p;         p += (size_t)(N + 1) * 4; p = align_up(p, 256);
    float*    dinv   = (float*)p;       p += (size_t)N * 4;       p = align_up(p, 256);
    float*    bnsc   = (float*)p;       p += D_OUT * 4;
    float*    bnsh   = (float*)p;       p += D_OUT * 4;           p = align_up(p, 256);
    __bf16*   whi    = (__bf16*)p;      p += (size_t)D_OUT * D_IN * 2; p = align_up(p, 256);
    __bf16*   wlo    = (__bf16*)p;      p += (size_t)D_OUT * D_IN * 2; p = align_up(p, 256);
    __bf16*   yb     = (__bf16*)p;      p += (size_t)N * D_OUT * 2;    p = align_up(p, 256);
    int*      srcs   = (int*)p;         p += (size_t)E * 4;       p = align_up(p, 256);
    unsigned* pairs  = (unsigned*)p;    // nbins * BINCAP * 4 bytes (~7.2 MB)

    k_prep<<<10, 256, 0, stream>>>(W, whi, wlo, bias, gamma, beta, rmean, rvar,
                                   bnsc, bnsh, bincur, nbins);
    k_part<<<(E + PCHUNK - 1) / PCHUNK, 256, 0, stream>>>(ei, bincur, pairs, E, nbins);
    k_binscan<<<1, 256, 0, stream>>>(bincur, binoff, off, nbins, N);
    k_fill3<<<nbins, 256, 0, stream>>>(pairs, bincur, binoff, off, dinv, srcs, N);
    k_gemm<<<(N + 63) / 64, 256, 0, stream>>>(x, whi, wlo, dinv, yb, N);
    k_aggregate<<<(N + 3) / 4, 256, 0, stream>>>(off, srcs, (const unsigned*)yb,
                                                 dinv, bnsc, bnsh, out, N);
}